// Round 1
// baseline (63.701 us; speedup 1.0000x reference)
//
#include <hip/hip_runtime.h>

// Problem constants (from reference setup_inputs)
#define BB 4
#define CC 128
#define HH 256
#define WW 256
#define NKP 4096
#define INV_RATIO (1.0f / 16.0f)

__global__ __launch_bounds__(256) void interp_kernel(
    const float* __restrict__ feature,     // B x C x H x W
    const float* __restrict__ keypoints,   // B x N x 2
    float* __restrict__ out)               // B x C x N
{
    int idx = blockIdx.x * blockDim.x + threadIdx.x;
    const int total = BB * CC * NKP;
    if (idx >= total) return;

    int n  = idx & (NKP - 1);
    int bc = idx >> 12;           // idx / NKP
    int c  = bc & (CC - 1);
    int b  = bc >> 7;             // bc / CC

    // keypoint in feature-map coords
    const float2 kpv = *reinterpret_cast<const float2*>(keypoints + ((size_t)(b * NKP + n)) * 2);
    float kx = kpv.x * INV_RATIO;
    float ky = kpv.y * INV_RATIO;

    float fx = fmaxf(floorf(kx), 0.0f);
    float fy = fmaxf(floorf(ky), 0.0f);
    float cx = fminf(ceilf(kx), (float)(WW - 1));
    float cy = fminf(ceilf(ky), (float)(HH - 1));

    float ux = kx - fx;            // weight for upper corner (x)
    float uy = ky - fy;
    float lx = 1.0f - ux;
    float ly = 1.0f - uy;

    int x0 = (int)fx, x1 = (int)cx, y0 = (int)fy, y1 = (int)cy;

    const float* f = feature + ((size_t)(b * CC + c)) * (HH * WW);
    float v00 = f[y0 * WW + x0];
    float v01 = f[y0 * WW + x1];
    float v10 = f[y1 * WW + x0];
    float v11 = f[y1 * WW + x1];

    float val = lx * ly * v00 + ux * ly * v01 + lx * uy * v10 + ux * uy * v11;

    // mask: mean over the two coords of (kp > 1e-10)
    float mask = 0.5f * ((kx > 1e-10f ? 1.0f : 0.0f) + (ky > 1e-10f ? 1.0f : 0.0f));

    out[idx] = val * mask;
}

extern "C" void kernel_launch(void* const* d_in, const int* in_sizes, int n_in,
                              void* d_out, int out_size, void* d_ws, size_t ws_size,
                              hipStream_t stream) {
    const float* feature   = (const float*)d_in[0];
    const float* keypoints = (const float*)d_in[1];
    float* out = (float*)d_out;

    const int total = BB * CC * NKP;
    const int block = 256;
    const int grid  = (total + block - 1) / block;
    interp_kernel<<<grid, block, 0, stream>>>(feature, keypoints, out);
}

// Round 6
// 36.147 us; speedup vs baseline: 1.7622x; 1.7622x over previous
//
#include <hip/hip_runtime.h>

// Problem constants (from reference setup_inputs)
#define BB 4
#define CC 128
#define HH 256
#define WW 256
#define NKP 4096
#define INV_RATIO (1.0f / 16.0f)
#define CPT 4                 // channels per thread
#define NXCD 8

// Grid: BB * (CC/CPT) * (NKP/256) = 4 * 32 * 16 = 2048 blocks of 256 threads.
// Swizzle: map-group g (= b*32 + c0/CPT) is pinned to XCD g%8; the 16 blocks
// covering its 4096 keypoints are consecutive slots on that XCD, so each
// channel-map group (4 maps = 1 MB) is fetched into exactly one L2 and the
// ~3x keypoint line-reuse is served from L2, not L3/HBM.
//
// Coverage proof (determinism): bid in [0,2048) decodes bijectively to
// (g in [0,128), j in [0,16)); each (g,j,tid) writes 4 distinct outputs
// (b, c0..c0+3, n) exactly once; no two threads share an output address.
__global__ __launch_bounds__(256) void interp_kernel(
    const float* __restrict__ feature,     // B x C x H x W
    const float* __restrict__ keypoints,   // B x N x 2
    float* __restrict__ out)               // B x C x N
{
    // decode swizzled block id
    int bid   = blockIdx.x;        // 0..2047
    int xcd   = bid & (NXCD - 1);
    int slot  = bid >> 3;          // 0..255
    int gloc  = slot >> 4;         // group index within this XCD, 0..15
    int j     = slot & 15;         // keypoint-block within group, 0..15
    int g     = gloc * NXCD + xcd; // map-group id, 0..127
    int b     = g >> 5;            // g / 32
    int c0    = (g & 31) * CPT;    // first channel of this group
    int n     = j * 256 + threadIdx.x;

    // keypoint in feature-map coords (two scalar loads; no aliasing cast)
    const float* kp = keypoints + ((size_t)(b * NKP + n)) * 2;
    float kx = kp[0] * INV_RATIO;
    float ky = kp[1] * INV_RATIO;

    float fx = fmaxf(floorf(kx), 0.0f);
    float fy = fmaxf(floorf(ky), 0.0f);
    float cx = fminf(ceilf(kx), (float)(WW - 1));
    float cy = fminf(ceilf(ky), (float)(HH - 1));

    float ux = kx - fx;            // weight for upper corner (x)
    float uy = ky - fy;
    float lx = 1.0f - ux;
    float ly = 1.0f - uy;

    float w00 = lx * ly, w01 = ux * ly, w10 = lx * uy, w11 = ux * uy;

    int x0 = (int)fx, x1 = (int)cx, y0 = (int)fy, y1 = (int)cy;
    int i00 = y0 * WW + x0, i01 = y0 * WW + x1;
    int i10 = y1 * WW + x0, i11 = y1 * WW + x1;

    // mask: mean over the two coords of (kp > 1e-10)
    float mask = 0.5f * ((kx > 1e-10f ? 1.0f : 0.0f) + (ky > 1e-10f ? 1.0f : 0.0f));

    const float* f = feature + ((size_t)(b * CC + c0)) * (HH * WW);

    float v00[CPT], v01[CPT], v10[CPT], v11[CPT];
    #pragma unroll
    for (int k = 0; k < CPT; ++k) {
        const float* fc = f + (size_t)k * (HH * WW);
        v00[k] = fc[i00];
        v01[k] = fc[i01];
        v10[k] = fc[i10];
        v11[k] = fc[i11];
    }

    #pragma unroll
    for (int k = 0; k < CPT; ++k) {
        float val = w00 * v00[k] + w01 * v01[k] + w10 * v10[k] + w11 * v11[k];
        out[((size_t)(b * CC + c0 + k)) * NKP + n] = val * mask;
    }
}

extern "C" void kernel_launch(void* const* d_in, const int* in_sizes, int n_in,
                              void* d_out, int out_size, void* d_ws, size_t ws_size,
                              hipStream_t stream) {
    const float* feature   = (const float*)d_in[0];
    const float* keypoints = (const float*)d_in[1];
    float* out = (float*)d_out;

    const int grid = BB * (CC / CPT) * (NKP / 256);  // 2048
    interp_kernel<<<grid, 256, 0, stream>>>(feature, keypoints, out);
}

// Round 7
// 36.127 us; speedup vs baseline: 1.7633x; 1.0006x over previous
//
#include <hip/hip_runtime.h>

// Problem constants (from reference setup_inputs)
#define BB 4
#define CC 128
#define HH 256
#define WW 256
#define NKP 4096
#define INV_RATIO (1.0f / 16.0f)
#define CPT 8                 // channels per thread
#define NXCD 8

// Grid: BB * (CC/CPT) * (NKP/256) = 4 * 16 * 16 = 1024 blocks of 256 threads.
// Swizzle: map-group g (= b*16 + c0/CPT) is pinned to XCD g%8 (64 groups,
// 64%8==0 -> bijective); the 16 blocks covering its 4096 keypoints are
// consecutive slots on that XCD, so each 8-map group (2 MB) is fetched into
// exactly one L2 and keypoint line-reuse is served from L2, not L3/HBM.
//
// Determinism: bid in [0,1024) decodes bijectively to (g in [0,64), j in
// [0,16)); each (g,j,tid) writes 8 distinct outputs exactly once.
__global__ __launch_bounds__(256) void interp_kernel(
    const float* __restrict__ feature,     // B x C x H x W
    const float* __restrict__ keypoints,   // B x N x 2
    float* __restrict__ out)               // B x C x N
{
    int bid   = blockIdx.x;        // 0..1023
    int xcd   = bid & (NXCD - 1);
    int slot  = bid >> 3;          // 0..127
    int gloc  = slot >> 4;         // group index within this XCD, 0..7
    int j     = slot & 15;         // keypoint-block within group, 0..15
    int g     = gloc * NXCD + xcd; // map-group id, 0..63
    int b     = g >> 4;            // g / 16
    int c0    = (g & 15) * CPT;    // first channel of this group
    int n     = j * 256 + threadIdx.x;

    // keypoint in feature-map coords (scalar loads; compiler merges)
    const float* kp = keypoints + ((size_t)(b * NKP + n)) * 2;
    float kx = kp[0] * INV_RATIO;
    float ky = kp[1] * INV_RATIO;

    float fx = fmaxf(floorf(kx), 0.0f);
    float fy = fmaxf(floorf(ky), 0.0f);

    int x0 = (int)fx, y0 = (int)fy;
    int x1 = min(x0 + 1, WW - 1);      // == clamped ceil; when kx integral the
    int y1 = min(y0 + 1, HH - 1);      // extra corner carries weight 0

    float ux = kx - fx;            // weight for upper corner (x)
    float uy = ky - fy;
    float lx = 1.0f - ux;
    float ly = 1.0f - uy;

    // mask folded into the 4 weights (mean over 2 coords of kp > 1e-10)
    float mask = 0.5f * ((kx > 1e-10f ? 1.0f : 0.0f) + (ky > 1e-10f ? 1.0f : 0.0f));
    float w00 = lx * ly * mask, w01 = ux * ly * mask;
    float w10 = lx * uy * mask, w11 = ux * uy * mask;

    int i00 = y0 * WW + x0, i01 = y0 * WW + x1;
    int i10 = y1 * WW + x0, i11 = y1 * WW + x1;

    const float* f = feature + ((size_t)(b * CC + c0)) * (HH * WW);

    float v00[CPT], v01[CPT], v10[CPT], v11[CPT];
    #pragma unroll
    for (int k = 0; k < CPT; ++k) {
        const float* fc = f + (size_t)k * (HH * WW);
        v00[k] = fc[i00];
        v01[k] = fc[i01];
        v10[k] = fc[i10];
        v11[k] = fc[i11];
    }

    float* o = out + ((size_t)(b * CC + c0)) * NKP + n;
    #pragma unroll
    for (int k = 0; k < CPT; ++k) {
        float val = w00 * v00[k] + w01 * v01[k] + w10 * v10[k] + w11 * v11[k];
        __builtin_nontemporal_store(val, o + (size_t)k * NKP);
    }
}

extern "C" void kernel_launch(void* const* d_in, const int* in_sizes, int n_in,
                              void* d_out, int out_size, void* d_ws, size_t ws_size,
                              hipStream_t stream) {
    const float* feature   = (const float*)d_in[0];
    const float* keypoints = (const float*)d_in[1];
    float* out = (float*)d_out;

    const int grid = BB * (CC / CPT) * (NKP / 256);  // 1024
    interp_kernel<<<grid, 256, 0, stream>>>(feature, keypoints, out);
}

// Round 8
// 30.388 us; speedup vs baseline: 2.0963x; 1.1889x over previous
//
#include <hip/hip_runtime.h>

// Problem constants (from reference setup_inputs)
#define BB 4
#define CC 128
#define HH 256
#define WW 256
#define NKP 4096
#define INV_RATIO (1.0f / 16.0f)
#define CPT 4                 // channels per thread
#define NXCD 8

typedef float fpair __attribute__((ext_vector_type(2)));

// Grid: BB * (CC/CPT) * (NKP/256) = 2048 blocks of 256 threads.
// Swizzle: map-group g (= b*32 + c0/CPT) pinned to XCD g%8 (128 groups,
// 128%8==0 -> bijective). Each 4-map group (1 MB) is fetched into exactly
// one L2; keypoint line-reuse served from L2.
//
// Key change vs R7: per (kp, channel) the two x-corners of each row are
// fetched with ONE 8-byte load (memcpy -> global_load_dwordx2, 4B-aligned
// OK on gfx950) instead of two dword gathers: 8.4M -> 4.2M scattered
// transactions. Row-pair start clamped to W-2; the x0==W-1 (kx==255.0)
// case is folded into the x-weights (wlx=0, wux=1 -> picks pair.y with
// total weight lx+ux=1).
__global__ __launch_bounds__(256) void interp_kernel(
    const float* __restrict__ feature,     // B x C x H x W
    const float* __restrict__ keypoints,   // B x N x 2
    float* __restrict__ out)               // B x C x N
{
    int bid   = blockIdx.x;        // 0..2047
    int xcd   = bid & (NXCD - 1);
    int slot  = bid >> 3;          // 0..255
    int gloc  = slot >> 4;         // 0..15
    int j     = slot & 15;         // 0..15
    int g     = gloc * NXCD + xcd; // 0..127
    int b     = g >> 5;
    int c0    = (g & 31) * CPT;
    int n     = j * 256 + threadIdx.x;

    const float* kp = keypoints + ((size_t)(b * NKP + n)) * 2;
    float kx = kp[0] * INV_RATIO;
    float ky = kp[1] * INV_RATIO;

    float fx = fmaxf(floorf(kx), 0.0f);
    float fy = fmaxf(floorf(ky), 0.0f);
    int x0 = (int)fx, y0 = (int)fy;

    float ux = kx - fx, uy = ky - fy;
    float lx = 1.0f - ux, ly = 1.0f - uy;

    // clamp pair start; fold boundary select into weights (once per kp)
    bool selx = (x0 >= WW - 1);
    bool sely = (y0 >= HH - 1);
    int xp = selx ? (WW - 2) : x0;
    int yp = sely ? (HH - 2) : y0;
    float wlx = selx ? 0.0f : lx, wux = selx ? 1.0f : ux;
    float wly = sely ? 0.0f : ly, wuy = sely ? 1.0f : uy;

    // mask folded into the 4 weights
    float mask = 0.5f * ((kx > 1e-10f ? 1.0f : 0.0f) + (ky > 1e-10f ? 1.0f : 0.0f));
    float w00 = wlx * wly * mask, w01 = wux * wly * mask;
    float w10 = wlx * wuy * mask, w11 = wux * wuy * mask;

    int i0 = yp * WW + xp;         // row y-lo pair
    int i1 = i0 + WW;              // row y-hi pair

    const float* f = feature + ((size_t)(b * CC + c0)) * (HH * WW);

    fpair r0[CPT], r1[CPT];
    #pragma unroll
    for (int k = 0; k < CPT; ++k) {
        const float* fc = f + (size_t)k * (HH * WW);
        __builtin_memcpy(&r0[k], fc + i0, sizeof(fpair));
        __builtin_memcpy(&r1[k], fc + i1, sizeof(fpair));
    }

    float* o = out + ((size_t)(b * CC + c0)) * NKP + n;
    #pragma unroll
    for (int k = 0; k < CPT; ++k) {
        float val = w00 * r0[k].x + w01 * r0[k].y
                  + w10 * r1[k].x + w11 * r1[k].y;
        __builtin_nontemporal_store(val, o + (size_t)k * NKP);
    }
}

extern "C" void kernel_launch(void* const* d_in, const int* in_sizes, int n_in,
                              void* d_out, int out_size, void* d_ws, size_t ws_size,
                              hipStream_t stream) {
    const float* feature   = (const float*)d_in[0];
    const float* keypoints = (const float*)d_in[1];
    float* out = (float*)d_out;

    const int grid = BB * (CC / CPT) * (NKP / 256);  // 2048
    interp_kernel<<<grid, 256, 0, stream>>>(feature, keypoints, out);
}